// Round 1
// baseline (576.605 us; speedup 1.0000x reference)
//
#include <hip/hip_runtime.h>
#include <hip/hip_bf16.h>
#include <stdint.h>

// VQ nearest-codebook: B=8,N=4096,C=256,K=8192
// dist(i,j) = |x_i|^2 + |c_j|^2 - 2 x_i.c_j ; outputs codes[BN,C], idx[BN], dist[BN]
// Strategy: fp16x2 split (x*64 = hi+lo) -> 3 MFMA GEMMs at bf16 rate, fused argmin.

#define M_ROWS 32768   // B*N
#define KCODES 8192
#define CDIM   256
#define BM 128
#define BN 128
#define BK 32
#define NSPLIT 4
#define KCHUNK (KCODES / NSPLIT)   // 2048
#define NTILES (KCHUNK / BN)       // 16
#define KSTEPS (CDIM / BK)         // 8

typedef _Float16 f16x8 __attribute__((ext_vector_type(8)));
typedef float    f32x4 __attribute__((ext_vector_type(4)));

// ---------------- prep: fp16x2 split (scaled by 64) + row sq-norms ----------------
__global__ void vq_prep(const float* __restrict__ x, const float* __restrict__ cb,
                        _Float16* __restrict__ xhi, _Float16* __restrict__ xlo,
                        _Float16* __restrict__ cbhi, _Float16* __restrict__ cblo,
                        float* __restrict__ xsq, float* __restrict__ cbsq) {
  const int row = blockIdx.x;
  const int tid = threadIdx.x;
  const float* src;
  _Float16 *dhi, *dlo;
  float* dsq;
  if (row < M_ROWS) {
    src = x + (size_t)row * CDIM;
    dhi = xhi + (size_t)row * CDIM; dlo = xlo + (size_t)row * CDIM;
    dsq = xsq + row;
  } else {
    const int r = row - M_ROWS;
    src = cb + (size_t)r * CDIM;
    dhi = cbhi + (size_t)r * CDIM; dlo = cblo + (size_t)r * CDIM;
    dsq = cbsq + r;
  }
  const float v = src[tid];
  const float vs = v * 64.0f;                 // scale keeps lo out of fp16 denormals
  const _Float16 h = (_Float16)vs;
  const _Float16 l = (_Float16)(vs - (float)h);
  dhi[tid] = h; dlo[tid] = l;
  float s = v * v;
  #pragma unroll
  for (int off = 32; off > 0; off >>= 1) s += __shfl_down(s, off, 64);
  __shared__ float ps[4];
  if ((tid & 63) == 0) ps[tid >> 6] = s;
  __syncthreads();
  if (tid == 0) *dsq = ps[0] + ps[1] + ps[2] + ps[3];
}

// ---------------- main: tiled MFMA GEMM with fused running argmin ----------------
__device__ __forceinline__ void gl16(const _Float16* g, _Float16* l) {
  __builtin_amdgcn_global_load_lds(
      (const __attribute__((address_space(1))) unsigned int*)g,
      (__attribute__((address_space(3))) unsigned int*)l, 16, 0, 0);
}

__global__ __launch_bounds__(256, 2) void vq_main(
    const _Float16* __restrict__ xhi, const _Float16* __restrict__ xlo,
    const _Float16* __restrict__ cbhi, const _Float16* __restrict__ cblo,
    const float* __restrict__ cbsq,
    float* __restrict__ pval, int* __restrict__ pidx) {
  const int tid  = threadIdx.x;
  const int wave = tid >> 6, lane = tid & 63;
  const int quad = lane >> 4, l15 = lane & 15;
  const int mbase  = blockIdx.x * BM;
  const int cbase0 = blockIdx.y * KCHUNK;
  const int wrow = (wave >> 1) * 64, wcol = (wave & 1) * 64;

  __shared__ alignas(16) _Float16 sAhi[BM * BK];
  __shared__ alignas(16) _Float16 sAlo[BM * BK];
  __shared__ alignas(16) _Float16 sBhi[BN * BK];
  __shared__ alignas(16) _Float16 sBlo[BN * BK];
  __shared__ float redv[2][BM];
  __shared__ int   redi[2][BM];

  // staging geometry: wave stages rows [wave*32, wave*32+32) of each 128x32 buffer,
  // 2 global_load_lds_dwordx4 per buffer (16 rows per wave-instr, lane -> row l>>2, k (l&3)*8)
  const int srl  = lane >> 2;
  const int scol = (lane & 3) * 8;

  float minv[4][4];
  int   mini[4][4];
  #pragma unroll
  for (int mf = 0; mf < 4; ++mf)
    #pragma unroll
    for (int i = 0; i < 4; ++i) { minv[mf][i] = __builtin_inff(); mini[mf][i] = 0; }

  for (int nt = 0; nt < NTILES; ++nt) {
    const int cb0 = cbase0 + nt * BN;
    f32x4 acc[4][4];
    #pragma unroll
    for (int mf = 0; mf < 4; ++mf)
      #pragma unroll
      for (int nf = 0; nf < 4; ++nf) {
        f32x4 z = {0.0f, 0.0f, 0.0f, 0.0f};
        acc[mf][nf] = z;
      }

    for (int ks = 0; ks < KSTEPS; ++ks) {
      const int kofs = ks * BK;
      __syncthreads();   // prior tile's ds_reads done before overwrite
      #pragma unroll
      for (int t = 0; t < 2; ++t) {
        const int row  = wave * 32 + t * 16 + srl;
        const int lofs = (wave * 32 + t * 16) * BK;        // wave-uniform LDS base
        const int ga = (mbase + row) * CDIM + kofs + scol;
        const int gb = (cb0 + row) * CDIM + kofs + scol;
        gl16(xhi + ga, sAhi + lofs);
        gl16(xlo + ga, sAlo + lofs);
        gl16(cbhi + gb, sBhi + lofs);
        gl16(cblo + gb, sBlo + lofs);
      }
      __syncthreads();   // vmcnt(0) drain: staged data visible

      f16x8 ah[4], al[4], bh[4], bl[4];
      #pragma unroll
      for (int mf = 0; mf < 4; ++mf) {
        const int o = (wrow + mf * 16 + l15) * BK + quad * 8;   // A[m=l&15][k=quad*8+j]
        ah[mf] = *(const f16x8*)(sAhi + o);
        al[mf] = *(const f16x8*)(sAlo + o);
      }
      #pragma unroll
      for (int nf = 0; nf < 4; ++nf) {
        const int o = (wcol + nf * 16 + l15) * BK + quad * 8;   // B^T[n=l&15][k=quad*8+j]
        bh[nf] = *(const f16x8*)(sBhi + o);
        bl[nf] = *(const f16x8*)(sBlo + o);
      }
      #pragma unroll
      for (int mf = 0; mf < 4; ++mf)
        #pragma unroll
        for (int nf = 0; nf < 4; ++nf) {
          acc[mf][nf] = __builtin_amdgcn_mfma_f32_16x16x32_f16(ah[mf], bh[nf], acc[mf][nf], 0, 0, 0);
          acc[mf][nf] = __builtin_amdgcn_mfma_f32_16x16x32_f16(ah[mf], bl[nf], acc[mf][nf], 0, 0, 0);
          acc[mf][nf] = __builtin_amdgcn_mfma_f32_16x16x32_f16(al[mf], bh[nf], acc[mf][nf], 0, 0, 0);
        }
    }

    // running min update: cand = cbsq[col] - 2*dot = fmaf(-2/4096, acc, cbsq)
    #pragma unroll
    for (int nf = 0; nf < 4; ++nf) {
      const int col = cb0 + wcol + nf * 16 + l15;   // C/D: col = lane&15 (+16*nf)
      const float cq = cbsq[col];
      #pragma unroll
      for (int mf = 0; mf < 4; ++mf)
        #pragma unroll
        for (int i = 0; i < 4; ++i) {
          const float v = fmaf(-0.00048828125f, acc[mf][nf][i], cq);
          if (v < minv[mf][i]) { minv[mf][i] = v; mini[mf][i] = col; }
        }
    }
  }

  // reduce across the 16 lanes sharing each row (C/D: row = quad*4+i), tie -> lower idx
  #pragma unroll
  for (int mf = 0; mf < 4; ++mf)
    #pragma unroll
    for (int i = 0; i < 4; ++i) {
      float v = minv[mf][i]; int ix = mini[mf][i];
      #pragma unroll
      for (int m = 1; m <= 8; m <<= 1) {
        const float ov = __shfl_xor(v, m, 64);
        const int   oi = __shfl_xor(ix, m, 64);
        if (ov < v || (ov == v && oi < ix)) { v = ov; ix = oi; }
      }
      if (l15 == 0) {
        const int rl = wrow + mf * 16 + quad * 4 + i;
        redv[wave & 1][rl] = v;
        redi[wave & 1][rl] = ix;
      }
    }
  __syncthreads();
  if (tid < BM) {
    float v0 = redv[0][tid]; int i0 = redi[0][tid];
    const float v1 = redv[1][tid]; const int i1 = redi[1][tid];
    if (v1 < v0 || (v1 == v0 && i1 < i0)) { v0 = v1; i0 = i1; }
    const size_t o = (size_t)blockIdx.y * M_ROWS + mbase + tid;
    pval[o] = v0; pidx[o] = i0;
  }
}

// ---------------- combine partial chunks -> final idx/dist ----------------
__global__ void vq_combine(const float* __restrict__ pval, const int* __restrict__ pidx,
                           const float* __restrict__ xsq,
                           float* __restrict__ outIdx, float* __restrict__ outDist,
                           int* __restrict__ fidx) {
  const int r = blockIdx.x * 256 + threadIdx.x;
  float bv = pval[r]; int bi = pidx[r];
  #pragma unroll
  for (int c = 1; c < NSPLIT; ++c) {
    const float v = pval[(size_t)c * M_ROWS + r];
    const int   i = pidx[(size_t)c * M_ROWS + r];
    if (v < bv || (v == bv && i < bi)) { bv = v; bi = i; }
  }
  fidx[r] = bi;
  outIdx[r] = (float)bi;        // exact for idx <= 8191
  outDist[r] = bv + xsq[r];
}

// ---------------- gather codes from original fp32 codebook ----------------
__global__ void vq_gather(const float* __restrict__ cb, const int* __restrict__ fidx,
                          float* __restrict__ codes) {
  const int t = blockIdx.x * 256 + threadIdx.x;
  const int r = t >> 6;
  const int c = (t & 63) * 4;
  const int k = fidx[r];
  const float4 v = *(const float4*)(cb + (size_t)k * CDIM + c);
  *(float4*)(codes + (size_t)r * CDIM + c) = v;
}

extern "C" void kernel_launch(void* const* d_in, const int* in_sizes, int n_in,
                              void* d_out, int out_size, void* d_ws, size_t ws_size,
                              hipStream_t stream) {
  const float* x  = (const float*)d_in[0];   // [8,4096,256] fp32
  const float* cb = (const float*)d_in[1];   // [8192,256] fp32
  float* out = (float*)d_out;                // codes | idx | dist

  char* w = (char*)d_ws;                     // needs ~43.3 MB
  _Float16* xhi  = (_Float16*)(w);
  _Float16* xlo  = (_Float16*)(w + 16777216);
  _Float16* cbhi = (_Float16*)(w + 33554432);
  _Float16* cblo = (_Float16*)(w + 37748736);
  float* xsq  = (float*)(w + 41943040);
  float* cbsq = (float*)(w + 42074112);
  float* pval = (float*)(w + 42106880);
  int*   pidx = (int*)  (w + 42631168);
  int*   fidx = (int*)  (w + 43155456);

  vq_prep<<<M_ROWS + KCODES, 256, 0, stream>>>(x, cb, xhi, xlo, cbhi, cblo, xsq, cbsq);
  vq_main<<<dim3(M_ROWS / BM, NSPLIT), 256, 0, stream>>>(xhi, xlo, cbhi, cblo, cbsq, pval, pidx);
  vq_combine<<<M_ROWS / 256, 256, 0, stream>>>(pval, pidx, xsq,
                                               out + 8388608, out + 8421376, fidx);
  vq_gather<<<M_ROWS * 64 / 256, 256, 0, stream>>>(cb, fidx, out);
}

// Round 2
// 437.207 us; speedup vs baseline: 1.3188x; 1.3188x over previous
//
#include <hip/hip_runtime.h>
#include <hip/hip_bf16.h>
#include <stdint.h>

// VQ nearest-codebook: B=8,N=4096,C=256,K=8192
// dist(i,j) = |x_i|^2 + |c_j|^2 - 2 x_i.c_j ; outputs codes[BN,C], idx[BN], dist[BN]
// fp16x2 split (x*64 = hi+lo) -> 3 MFMA GEMMs at f16 rate, fused argmin.
// R2: XOR bank-conflict swizzle + 64x128 wave tiles (block 128x256).

#define M_ROWS 32768   // B*N
#define KCODES 8192
#define CDIM   256
#define BM 128
#define BNT 256        // codes per block tile
#define BK 32
#define NSPLIT 4
#define KCHUNK (KCODES / NSPLIT)   // 2048
#define NTILES (KCHUNK / BNT)      // 8
#define KSTEPS (CDIM / BK)         // 8

typedef _Float16 f16x8 __attribute__((ext_vector_type(8)));
typedef _Float16 f16x4 __attribute__((ext_vector_type(4)));
typedef float    f32x4 __attribute__((ext_vector_type(4)));

// ---------------- prep: fp16x2 split (scaled by 64) + row sq-norms ----------------
__global__ void vq_prep(const float* __restrict__ x, const float* __restrict__ cb,
                        _Float16* __restrict__ xhi, _Float16* __restrict__ xlo,
                        _Float16* __restrict__ cbhi, _Float16* __restrict__ cblo,
                        float* __restrict__ xsq, float* __restrict__ cbsq) {
  const int wave = threadIdx.x >> 6, lane = threadIdx.x & 63;
  const int row = blockIdx.x * 4 + wave;     // one wave per row
  const float* src;
  _Float16 *dhi, *dlo;
  float* dsq;
  if (row < M_ROWS) {
    src = x + (size_t)row * CDIM;
    dhi = xhi + (size_t)row * CDIM; dlo = xlo + (size_t)row * CDIM;
    dsq = xsq + row;
  } else {
    const int r = row - M_ROWS;
    src = cb + (size_t)r * CDIM;
    dhi = cbhi + (size_t)r * CDIM; dlo = cblo + (size_t)r * CDIM;
    dsq = cbsq + r;
  }
  const float4 v = *(const float4*)(src + lane * 4);
  f16x4 h, l;
  float s = 0.0f;
  const float vs0 = v.x * 64.0f; h[0] = (_Float16)vs0; l[0] = (_Float16)(vs0 - (float)h[0]); s += v.x * v.x;
  const float vs1 = v.y * 64.0f; h[1] = (_Float16)vs1; l[1] = (_Float16)(vs1 - (float)h[1]); s += v.y * v.y;
  const float vs2 = v.z * 64.0f; h[2] = (_Float16)vs2; l[2] = (_Float16)(vs2 - (float)h[2]); s += v.z * v.z;
  const float vs3 = v.w * 64.0f; h[3] = (_Float16)vs3; l[3] = (_Float16)(vs3 - (float)h[3]); s += v.w * v.w;
  *(f16x4*)(dhi + lane * 4) = h;
  *(f16x4*)(dlo + lane * 4) = l;
  #pragma unroll
  for (int off = 32; off > 0; off >>= 1) s += __shfl_down(s, off, 64);
  if (lane == 0) *dsq = s;
}

// ---------------- main: tiled MFMA GEMM with fused running argmin ----------------
__device__ __forceinline__ void gl16(const _Float16* g, _Float16* l) {
  __builtin_amdgcn_global_load_lds(
      (const __attribute__((address_space(1))) unsigned int*)g,
      (__attribute__((address_space(3))) unsigned int*)l, 16, 0, 0);
}

__global__ __launch_bounds__(256, 2) void vq_main(
    const _Float16* __restrict__ xhi, const _Float16* __restrict__ xlo,
    const _Float16* __restrict__ cbhi, const _Float16* __restrict__ cblo,
    const float* __restrict__ cbsq,
    float* __restrict__ pval, int* __restrict__ pidx) {
  const int tid  = threadIdx.x;
  const int wave = tid >> 6, lane = tid & 63;
  const int quad = lane >> 4, l15 = lane & 15;
  const int mbase  = blockIdx.x * BM;
  const int cbase0 = blockIdx.y * KCHUNK;
  const int wrow = (wave >> 1) * 64;         // row half
  const int wcol = (wave & 1) * 128;         // col half

  __shared__ alignas(16) _Float16 sAhi[BM * BK];    //  8 KB
  __shared__ alignas(16) _Float16 sAlo[BM * BK];    //  8 KB
  __shared__ alignas(16) _Float16 sBhi[BNT * BK];   // 16 KB
  __shared__ alignas(16) _Float16 sBlo[BNT * BK];   // 16 KB
  __shared__ float redv[2][BM];
  __shared__ int   redi[2][BM];

  // staging: each global_load_lds_dwordx4 covers 16 rows (64 lanes x 16B).
  // lane -> row lane>>2, 16B-slot lane&3 ; global slot XOR-swizzled by (row>>1)&3
  // so that LDS(row, p) holds Global(row, p ^ ((row>>1)&3)).
  const int srl  = lane >> 2;
  const int scol = (((lane & 3) ^ ((lane >> 3) & 3)) << 3);  // halves
  // fragment read de-swizzle: p = quad ^ ((row>>1)&3), row ≡ l15 (mod 16)
  const int fcol = ((quad ^ ((l15 >> 1) & 3)) << 3);         // halves

  float minv[4][4];
  int   mini[4][4];
  #pragma unroll
  for (int mf = 0; mf < 4; ++mf)
    #pragma unroll
    for (int i = 0; i < 4; ++i) { minv[mf][i] = __builtin_inff(); mini[mf][i] = 0; }

  for (int nt = 0; nt < NTILES; ++nt) {
    const int cb0 = cbase0 + nt * BNT;
    f32x4 acc[4][8];
    #pragma unroll
    for (int mf = 0; mf < 4; ++mf)
      #pragma unroll
      for (int nf = 0; nf < 8; ++nf) {
        f32x4 z = {0.0f, 0.0f, 0.0f, 0.0f};
        acc[mf][nf] = z;
      }

    for (int ks = 0; ks < KSTEPS; ++ks) {
      const int kofs = ks * BK;
      __syncthreads();   // prior step's ds_reads done before overwrite
      // A: 8 slices of 16 rows per buffer -> 2 per wave
      #pragma unroll
      for (int t = 0; t < 2; ++t) {
        const int rb  = wave * 32 + t * 16;
        const int ga  = (mbase + rb + srl) * CDIM + kofs + scol;
        gl16(xhi + ga, sAhi + rb * BK);
        gl16(xlo + ga, sAlo + rb * BK);
      }
      // B: 16 slices per buffer -> 4 per wave
      #pragma unroll
      for (int t = 0; t < 4; ++t) {
        const int rb  = wave * 64 + t * 16;
        const int gb  = (cb0 + rb + srl) * CDIM + kofs + scol;
        gl16(cbhi + gb, sBhi + rb * BK);
        gl16(cblo + gb, sBlo + rb * BK);
      }
      __syncthreads();   // staged data visible

      f16x8 ah[4], al[4];
      #pragma unroll
      for (int mf = 0; mf < 4; ++mf) {
        const int o = (wrow + mf * 16 + l15) * BK + fcol;   // A[m=l15][k=quad*8+j]
        ah[mf] = *(const f16x8*)(sAhi + o);
        al[mf] = *(const f16x8*)(sAlo + o);
      }
      #pragma unroll
      for (int nf = 0; nf < 8; ++nf) {
        const int o = (wcol + nf * 16 + l15) * BK + fcol;   // B^T[n=l15][k=quad*8+j]
        const f16x8 bh = *(const f16x8*)(sBhi + o);
        const f16x8 bl = *(const f16x8*)(sBlo + o);
        #pragma unroll
        for (int mf = 0; mf < 4; ++mf) {
          acc[mf][nf] = __builtin_amdgcn_mfma_f32_16x16x32_f16(ah[mf], bh, acc[mf][nf], 0, 0, 0);
          acc[mf][nf] = __builtin_amdgcn_mfma_f32_16x16x32_f16(ah[mf], bl, acc[mf][nf], 0, 0, 0);
          acc[mf][nf] = __builtin_amdgcn_mfma_f32_16x16x32_f16(al[mf], bh, acc[mf][nf], 0, 0, 0);
        }
      }
    }

    // running min: cand = cbsq[col] - 2*dot = fmaf(-2/4096, acc, cbsq)
    #pragma unroll
    for (int nf = 0; nf < 8; ++nf) {
      const int col = cb0 + wcol + nf * 16 + l15;   // C/D: col = lane&15
      const float cq = cbsq[col];
      #pragma unroll
      for (int mf = 0; mf < 4; ++mf)
        #pragma unroll
        for (int i = 0; i < 4; ++i) {
          const float v = fmaf(-0.00048828125f, acc[mf][nf][i], cq);
          if (v < minv[mf][i]) { minv[mf][i] = v; mini[mf][i] = col; }
        }
    }
  }

  // reduce the 16 lanes sharing each row (C/D: row = quad*4+i), tie -> lower idx
  #pragma unroll
  for (int mf = 0; mf < 4; ++mf)
    #pragma unroll
    for (int i = 0; i < 4; ++i) {
      float v = minv[mf][i]; int ix = mini[mf][i];
      #pragma unroll
      for (int m = 1; m <= 8; m <<= 1) {
        const float ov = __shfl_xor(v, m, 64);
        const int   oi = __shfl_xor(ix, m, 64);
        if (ov < v || (ov == v && oi < ix)) { v = ov; ix = oi; }
      }
      if (l15 == 0) {
        const int rl = wrow + mf * 16 + quad * 4 + i;
        redv[wave & 1][rl] = v;
        redi[wave & 1][rl] = ix;
      }
    }
  __syncthreads();
  if (tid < BM) {
    float v0 = redv[0][tid]; int i0 = redi[0][tid];
    const float v1 = redv[1][tid]; const int i1 = redi[1][tid];
    if (v1 < v0 || (v1 == v0 && i1 < i0)) { v0 = v1; i0 = i1; }
    const size_t o = (size_t)blockIdx.y * M_ROWS + mbase + tid;
    pval[o] = v0; pidx[o] = i0;
  }
}

// ---------------- combine partial chunks -> final idx/dist ----------------
__global__ void vq_combine(const float* __restrict__ pval, const int* __restrict__ pidx,
                           const float* __restrict__ xsq,
                           float* __restrict__ outIdx, float* __restrict__ outDist,
                           int* __restrict__ fidx) {
  const int r = blockIdx.x * 256 + threadIdx.x;
  float bv = pval[r]; int bi = pidx[r];
  #pragma unroll
  for (int c = 1; c < NSPLIT; ++c) {
    const float v = pval[(size_t)c * M_ROWS + r];
    const int   i = pidx[(size_t)c * M_ROWS + r];
    if (v < bv || (v == bv && i < bi)) { bv = v; bi = i; }
  }
  fidx[r] = bi;
  outIdx[r] = (float)bi;        // exact for idx <= 8191
  outDist[r] = bv + xsq[r];
}

// ---------------- gather codes from original fp32 codebook ----------------
__global__ void vq_gather(const float* __restrict__ cb, const int* __restrict__ fidx,
                          float* __restrict__ codes) {
  const int t = blockIdx.x * 256 + threadIdx.x;
  const int r = t >> 6;
  const int c = (t & 63) * 4;
  const int k = fidx[r];
  const float4 v = *(const float4*)(cb + (size_t)k * CDIM + c);
  *(float4*)(codes + (size_t)r * CDIM + c) = v;
}

extern "C" void kernel_launch(void* const* d_in, const int* in_sizes, int n_in,
                              void* d_out, int out_size, void* d_ws, size_t ws_size,
                              hipStream_t stream) {
  const float* x  = (const float*)d_in[0];   // [8,4096,256] fp32
  const float* cb = (const float*)d_in[1];   // [8192,256] fp32
  float* out = (float*)d_out;                // codes | idx | dist

  char* w = (char*)d_ws;                     // needs ~43.3 MB
  _Float16* xhi  = (_Float16*)(w);
  _Float16* xlo  = (_Float16*)(w + 16777216);
  _Float16* cbhi = (_Float16*)(w + 33554432);
  _Float16* cblo = (_Float16*)(w + 37748736);
  float* xsq  = (float*)(w + 41943040);
  float* cbsq = (float*)(w + 42074112);
  float* pval = (float*)(w + 42106880);
  int*   pidx = (int*)  (w + 42631168);
  int*   fidx = (int*)  (w + 43155456);

  vq_prep<<<(M_ROWS + KCODES) / 4, 256, 0, stream>>>(x, cb, xhi, xlo, cbhi, cblo, xsq, cbsq);
  vq_main<<<dim3(M_ROWS / BM, NSPLIT), 256, 0, stream>>>(xhi, xlo, cbhi, cblo, cbsq, pval, pidx);
  vq_combine<<<M_ROWS / 256, 256, 0, stream>>>(pval, pidx, xsq,
                                               out + 8388608, out + 8421376, fidx);
  vq_gather<<<M_ROWS * 64 / 256, 256, 0, stream>>>(cb, fidx, out);
}